// Round 5
// baseline (337.099 us; speedup 1.0000x reference)
//
#include <hip/hip_runtime.h>
#include <hip/hip_bf16.h>
#include <float.h>
#include <math.h>

#define N_NODES 20000
#define N_EDGES 320000
#define ET      (N_EDGES + N_NODES)   // edges + self loops
#define DCH     512
#define D2      1024                   // fused l|r width
#define INCH    55
#define INCHP   64
#define OUTCH   49
#define OUTCHP  128
#define NB      130                    // degree buckets (clamped)

typedef _Float16 f16;
typedef _Float16 f16x2 __attribute__((ext_vector_type(2)));
typedef _Float16 f16x8 __attribute__((ext_vector_type(8)));
typedef float    f32x4 __attribute__((ext_vector_type(4)));

#define GPTR(p) ((const __attribute__((address_space(1))) void*)(p))
#define LPTR(p) ((__attribute__((address_space(3))) void*)(p))

// ---------------- fused prep: zeroing + conv_x + 5 weight transposes ----------
// segments by blockIdx.x:
//   [0,157)        zero counts(20000)+cursor(20000) and bcur(130)
//   [157,5157)     conv_x  (20000x64)
//   [5157,5165)    w1_l -> w1T               (Kp=64,  8 n-tiles)
//   [5165,5173)    w1_r -> w1T+512*64
//   [5173,5237)    w2_l -> w2T               (Kp=512, 8x8)
//   [5237,5301)    w2_r -> w2T+512*512
//   [5301,5317)    wcls -> wcT               (Kp=512, 2 n-tiles x 8 k-tiles)
__device__ __forceinline__ void transpose_tile(const float* __restrict__ w, f16* __restrict__ o,
                                               int K, int N, int Kp, int bx, int by, int t,
                                               f16 (*tile)[66]) {
    int k0 = by * 64, n0 = bx * 64;
    #pragma unroll
    for (int r = 0; r < 16; ++r) {
        int kl = (t >> 6) + r * 4, nl = t & 63;
        int gk = k0 + kl, gn = n0 + nl;
        tile[kl][nl] = (gk < K && gn < N) ? (f16)w[(size_t)gk * N + gn] : (f16)0.f;
    }
    __syncthreads();
    #pragma unroll
    for (int r = 0; r < 16; ++r) {
        int kl = t & 63, nl = (t >> 6) + r * 4;
        o[(size_t)(n0 + nl) * Kp + k0 + kl] = tile[kl][nl];
    }
}

__global__ __launch_bounds__(256) void prep_all(const float* __restrict__ x, f16* __restrict__ x_h,
                                                const float* __restrict__ w1l, const float* __restrict__ w1r,
                                                const float* __restrict__ w2l, const float* __restrict__ w2r,
                                                const float* __restrict__ wc,
                                                f16* __restrict__ w1T, f16* __restrict__ w2T,
                                                f16* __restrict__ wcT,
                                                int* __restrict__ zeroA,   // counts+cursor contiguous (40000)
                                                int* __restrict__ bcur) {
    __shared__ f16 tile[64][66];
    int b = blockIdx.x, t = threadIdx.x;
    if (b < 157) {
        int i = b * 256 + t;
        if (i < 40000) zeroA[i] = 0;
        else if (i < 40000 + NB) bcur[i - 40000] = 0;
        return;
    }
    b -= 157;
    if (b < 5000) {
        int i = b * 256 + t;
        int r = i >> 6, c = i & 63;
        x_h[i] = (c < INCH) ? (f16)x[r * INCH + c] : (f16)0.f;
        return;
    }
    b -= 5000;
    if (b < 8)  { transpose_tile(w1l, w1T, INCH, DCH, INCHP, b, 0, t, tile); return; }
    b -= 8;
    if (b < 8)  { transpose_tile(w1r, w1T + (size_t)DCH * INCHP, INCH, DCH, INCHP, b, 0, t, tile); return; }
    b -= 8;
    if (b < 64) { transpose_tile(w2l, w2T, DCH, DCH, DCH, b & 7, b >> 3, t, tile); return; }
    b -= 64;
    if (b < 64) { transpose_tile(w2r, w2T + (size_t)DCH * DCH, DCH, DCH, DCH, b & 7, b >> 3, t, tile); return; }
    b -= 64;
    transpose_tile(wc, wcT, DCH, OUTCH, DCH, b & 1, b >> 1, t, tile);
}

// ---------------- CSR build (by dst) ----------------
__global__ void count_kernel(const int* __restrict__ ei, int* __restrict__ counts) {
    int e = blockIdx.x * blockDim.x + threadIdx.x;
    if (e >= ET) return;
    int d = (e < N_EDGES) ? ei[N_EDGES + e] : (e - N_EDGES);
    atomicAdd(&counts[d], 1);
}

// node prefix-sum + degree-bucket histogram + bucket prefix-sum
__global__ void scan_kernel(const int* __restrict__ counts, int* __restrict__ row_ptr,
                            int* __restrict__ bbase) {
    __shared__ int sdata[1024];
    __shared__ int bh[NB];
    int t = threadIdx.x;
    if (t < NB) bh[t] = 0;
    __syncthreads();
    int per = (N_NODES + 1023) / 1024;
    int b = t * per, e = min(N_NODES, b + per);
    int sum = 0;
    for (int i = b; i < e; ++i) {
        int c = counts[i];
        sum += c;
        atomicAdd(&bh[min(c, NB - 1)], 1);
    }
    sdata[t] = sum;
    __syncthreads();
    for (int off = 1; off < 1024; off <<= 1) {
        int v = (t >= off) ? sdata[t - off] : 0;
        __syncthreads();
        sdata[t] += v;
        __syncthreads();
    }
    int run = (t == 0) ? 0 : sdata[t - 1];
    if (t == 0) row_ptr[0] = 0;
    for (int i = b; i < e; ++i) { run += counts[i]; row_ptr[i + 1] = run; }
    __syncthreads();
    if (t == 0) {
        int acc = 0;
        for (int j = 0; j < NB; ++j) { int v = bh[j]; bbase[j] = acc; acc += v; }
    }
}

__global__ void fill_kernel(const int* __restrict__ ei, const int* __restrict__ row_ptr,
                            int* __restrict__ cursor, int* __restrict__ esrc) {
    int e = blockIdx.x * blockDim.x + threadIdx.x;
    if (e >= ET) return;
    int s, d;
    if (e < N_EDGES) { s = ei[e]; d = ei[N_EDGES + e]; }
    else             { s = d = e - N_EDGES; }
    int pos = row_ptr[d] + atomicAdd(&cursor[d], 1);
    esrc[pos] = s;
}

// degree-sorted node permutation (bucket scatter; intra-bucket order arbitrary —
// outputs are per-node so result is order-independent)
__global__ void perm_kernel(const int* __restrict__ counts, const int* __restrict__ bbase,
                            int* __restrict__ bcur, int* __restrict__ perm) {
    int n = blockIdx.x * 256 + threadIdx.x;
    if (n >= N_NODES) return;
    int bkt = min(counts[n], NB - 1);
    int pos = bbase[bkt] + atomicAdd(&bcur[bkt], 1);
    perm[pos] = n;
}

// ---------------- fp16 MFMA GEMM (m97 + T2 XOR swizzle + T1 XCD swizzle) ----------
template<int OUT_F16, int DUAL>
__global__ __launch_bounds__(256) void gemm_f16(const f16* __restrict__ A,
                                                const f16* __restrict__ BT,
                                                const float* __restrict__ bl,
                                                const float* __restrict__ br,
                                                void* __restrict__ Cout,
                                                int M, int Ka, int Nv, int ldc) {
    __shared__ __align__(16) f16 As[128][64];
    __shared__ __align__(16) f16 Bs[128][64];
    const int tid = threadIdx.x;
    const int w = tid >> 6, lane = tid & 63;
    int nbx = gridDim.x;
    int nwg = nbx * gridDim.y;
    int bid = blockIdx.y * nbx + blockIdx.x;
    if ((nwg & 7) == 0) bid = (bid & 7) * (nwg >> 3) + (bid >> 3);
    const int m0 = (bid / nbx) * 128, n0 = (bid % nbx) * 128;
    const int wr = (w >> 1) * 64, wc = (w & 1) * 64;
    const int lrow = lane & 15, lk = lane >> 4;
    const int sw = lrow & 7;

    f32x4 acc[4][4] = {};

    for (int k0 = 0; k0 < Ka; k0 += 64) {
        #pragma unroll
        for (int i = 0; i < 4; ++i) {
            int idx = tid + 256 * i;
            int row = idx >> 3;
            int cg  = (idx & 7) ^ (row & 7);
            int gm = m0 + row; gm = gm < M ? gm : M - 1;
            const f16* gp = A + (size_t)gm * Ka + k0 + cg * 8;
            f16* lp = &As[0][0] + (size_t)(w * 64 + 256 * i) * 8;
            __builtin_amdgcn_global_load_lds(GPTR(gp), LPTR(lp), 16, 0, 0);
        }
        #pragma unroll
        for (int i = 0; i < 4; ++i) {
            int idx = tid + 256 * i;
            int row = idx >> 3;
            int cg  = (idx & 7) ^ (row & 7);
            const f16* gp = BT + (size_t)(n0 + row) * Ka + k0 + cg * 8;
            f16* lp = &Bs[0][0] + (size_t)(w * 64 + 256 * i) * 8;
            __builtin_amdgcn_global_load_lds(GPTR(gp), LPTR(lp), 16, 0, 0);
        }
        __syncthreads();
        #pragma unroll
        for (int kk = 0; kk < 64; kk += 32) {
            f16x8 af[4], bf[4];
            #pragma unroll
            for (int m = 0; m < 4; ++m)
                af[m] = *(const f16x8*)&As[wr + m * 16 + lrow][(((kk >> 3) + lk) ^ sw) * 8];
            #pragma unroll
            for (int n = 0; n < 4; ++n)
                bf[n] = *(const f16x8*)&Bs[wc + n * 16 + lrow][(((kk >> 3) + lk) ^ sw) * 8];
            #pragma unroll
            for (int m = 0; m < 4; ++m)
                #pragma unroll
                for (int n = 0; n < 4; ++n)
                    acc[m][n] = __builtin_amdgcn_mfma_f32_16x16x32_f16(af[m], bf[n], acc[m][n], 0, 0, 0);
        }
        __syncthreads();
    }

    const int orow = (lane >> 4) * 4, ocol = lane & 15;
    #pragma unroll
    for (int m = 0; m < 4; ++m) {
        #pragma unroll
        for (int r = 0; r < 4; ++r) {
            int gm = m0 + wr + m * 16 + orow + r;
            if (gm >= M) continue;
            #pragma unroll
            for (int n = 0; n < 4; ++n) {
                int gn = n0 + wc + n * 16 + ocol;
                if (gn >= Nv) continue;
                float bv = DUAL ? (gn < DCH ? bl[gn] : br[gn - DCH]) : bl[gn];
                float v = acc[m][n][r] + bv;
                if (OUT_F16) ((f16*)Cout)[(size_t)gm * ldc + gn] = (f16)v;
                else         ((float*)Cout)[(size_t)gm * ldc + gn] = v;
            }
        }
    }
}

// ---------------- fused GATv2 edge phase v5 ----------------
// Two degree-matched nodes per wave (perm pairing), 1-deep gather pipeline
// (issue next edge's rows before computing current), defer-max THR=8.
__global__ __launch_bounds__(256) void edge_agg5(const int* __restrict__ row_ptr,
                                                 const int* __restrict__ esrc,
                                                 const int* __restrict__ perm,
                                                 const f16* __restrict__ xlr,
                                                 const float* __restrict__ att,
                                                 const float* __restrict__ bias,
                                                 f16* __restrict__ out) {
    int wv = (blockIdx.x * 256 + threadIdx.x) >> 6;
    if (wv * 2 >= N_NODES) return;
    int n0 = perm[wv * 2], n1 = perm[wv * 2 + 1];
    int lane = threadIdx.x & 63;

    union U8 { f16x8 v; f16x2 q[4]; };
    U8 xr0, xr1;
    xr0.v = *(const f16x8*)(xlr + (size_t)n0 * D2 + DCH + lane * 8);
    xr1.v = *(const f16x8*)(xlr + (size_t)n1 * D2 + DCH + lane * 8);
    const float4* av = (const float4*)(att + lane * 8);
    float4 a0 = av[0], a1 = av[1];
    f16x2 at2[4] = { f16x2{(f16)a0.x, (f16)a0.y}, f16x2{(f16)a0.z, (f16)a0.w},
                     f16x2{(f16)a1.x, (f16)a1.y}, f16x2{(f16)a1.z, (f16)a1.w} };
    const f16x2 k02 = {(f16)0.2f, (f16)0.2f};

    int beg0 = row_ptr[n0], deg0 = row_ptr[n0 + 1] - beg0;
    int beg1 = row_ptr[n1], deg1 = row_ptr[n1 + 1] - beg1;
    int pre0 = (lane < deg0) ? esrc[beg0 + lane] : 0;
    int pre1 = (lane < deg1) ? esrc[beg1 + lane] : 0;

    float acc0[8] = {}, acc1[8] = {};
    float m0 = -FLT_MAX, m1 = -FLT_MAX, d0 = 0.f, d1 = 0.f;

    int dmax = deg0 > deg1 ? deg0 : deg1;
    int dcap = dmax < 64 ? dmax : 64;

    U8 c0, c1, x0, x1;
    {
        int s0 = __shfl(pre0, 0, 64), s1 = __shfl(pre1, 0, 64);
        c0.v = *(const f16x8*)(xlr + (size_t)s0 * D2 + lane * 8);
        c1.v = *(const f16x8*)(xlr + (size_t)s1 * D2 + lane * 8);
    }
    for (int p = 0; p < dcap; ++p) {
        int pn = (p + 1 < dcap) ? p + 1 : p;           // prefetch next (clamped)
        int t0 = __shfl(pre0, pn, 64), t1 = __shfl(pre1, pn, 64);
        x0.v = *(const f16x8*)(xlr + (size_t)t0 * D2 + lane * 8);
        x1.v = *(const f16x8*)(xlr + (size_t)t1 * D2 + lane * 8);

        float sc0 = 0.f, sc1 = 0.f;
        #pragma unroll
        for (int j = 0; j < 4; ++j) {
            f16x2 u0 = c0.q[j] + xr0.q[j];
            f16x2 u1 = c1.q[j] + xr1.q[j];
            f16x2 l0 = __builtin_elementwise_max(u0, u0 * k02);
            f16x2 l1 = __builtin_elementwise_max(u1, u1 * k02);
            sc0 = __builtin_amdgcn_fdot2(l0, at2[j], sc0, false);
            sc1 = __builtin_amdgcn_fdot2(l1, at2[j], sc1, false);
        }
        #pragma unroll
        for (int o = 8; o >= 1; o >>= 1) {
            sc0 += __shfl_xor(sc0, o, 64);
            sc1 += __shfl_xor(sc1, o, 64);
        }
        if (p >= deg0) sc0 = -INFINITY;
        if (p >= deg1) sc1 = -INFINITY;
        if (__any(sc0 > m0 + 8.f)) {                   // defer-max (T13)
            float mn = fmaxf(m0, sc0);
            float f = __expf(m0 - mn);
            d0 *= f;
            #pragma unroll
            for (int j = 0; j < 8; ++j) acc0[j] *= f;
            m0 = mn;
        }
        float w0 = __expf(sc0 - m0);
        d0 += w0;
        #pragma unroll
        for (int j = 0; j < 8; ++j) acc0[j] += w0 * (float)c0.v[j];
        if (__any(sc1 > m1 + 8.f)) {
            float mn = fmaxf(m1, sc1);
            float f = __expf(m1 - mn);
            d1 *= f;
            #pragma unroll
            for (int j = 0; j < 8; ++j) acc1[j] *= f;
            m1 = mn;
        }
        float w1 = __expf(sc1 - m1);
        d1 += w1;
        #pragma unroll
        for (int j = 0; j < 8; ++j) acc1[j] += w1 * (float)c1.v[j];
        c0 = x0; c1 = x1;
    }
    // rare tails: deg > 64 (paired nodes have similar degree, so usually both)
    for (int p = 64; p < deg0; ++p) {
        int s = esrc[beg0 + p];
        U8 u; u.v = *(const f16x8*)(xlr + (size_t)s * D2 + lane * 8);
        float sc0 = 0.f;
        #pragma unroll
        for (int j = 0; j < 4; ++j) {
            f16x2 t = u.q[j] + xr0.q[j];
            f16x2 l = __builtin_elementwise_max(t, t * k02);
            sc0 = __builtin_amdgcn_fdot2(l, at2[j], sc0, false);
        }
        #pragma unroll
        for (int o = 8; o >= 1; o >>= 1) sc0 += __shfl_xor(sc0, o, 64);
        if (__any(sc0 > m0 + 8.f)) {
            float mn = fmaxf(m0, sc0);
            float f = __expf(m0 - mn);
            d0 *= f;
            #pragma unroll
            for (int j = 0; j < 8; ++j) acc0[j] *= f;
            m0 = mn;
        }
        float w0 = __expf(sc0 - m0);
        d0 += w0;
        #pragma unroll
        for (int j = 0; j < 8; ++j) acc0[j] += w0 * (float)u.v[j];
    }
    for (int p = 64; p < deg1; ++p) {
        int s = esrc[beg1 + p];
        U8 u; u.v = *(const f16x8*)(xlr + (size_t)s * D2 + lane * 8);
        float sc1 = 0.f;
        #pragma unroll
        for (int j = 0; j < 4; ++j) {
            f16x2 t = u.q[j] + xr1.q[j];
            f16x2 l = __builtin_elementwise_max(t, t * k02);
            sc1 = __builtin_amdgcn_fdot2(l, at2[j], sc1, false);
        }
        #pragma unroll
        for (int o = 8; o >= 1; o >>= 1) sc1 += __shfl_xor(sc1, o, 64);
        if (__any(sc1 > m1 + 8.f)) {
            float mn = fmaxf(m1, sc1);
            float f = __expf(m1 - mn);
            d1 *= f;
            #pragma unroll
            for (int j = 0; j < 8; ++j) acc1[j] *= f;
            m1 = mn;
        }
        float w1 = __expf(sc1 - m1);
        d1 += w1;
        #pragma unroll
        for (int j = 0; j < 8; ++j) acc1[j] += w1 * (float)u.v[j];
    }

    const float4* bv = (const float4*)(bias + lane * 8);
    float4 b0 = bv[0], b1 = bv[1];
    float bf[8] = {b0.x, b0.y, b0.z, b0.w, b1.x, b1.y, b1.z, b1.w};
    float i0 = 1.f / d0, i1 = 1.f / d1;
    f16x8 o0, o1;
    #pragma unroll
    for (int j = 0; j < 8; ++j) {
        float v0 = acc0[j] * i0 + bf[j];
        float v1 = acc1[j] * i1 + bf[j];
        v0 = v0 > 0.f ? v0 : __expf(v0) - 1.f;   // ELU
        v1 = v1 > 0.f ? v1 : __expf(v1) - 1.f;
        o0[j] = (f16)v0;
        o1[j] = (f16)v1;
    }
    *(f16x8*)(out + (size_t)n0 * DCH + lane * 8) = o0;
    *(f16x8*)(out + (size_t)n1 * DCH + lane * 8) = o1;
}

// ---------------- launch ----------------
extern "C" void kernel_launch(void* const* d_in, const int* in_sizes, int n_in,
                              void* d_out, int out_size, void* d_ws, size_t ws_size,
                              hipStream_t stream) {
    const float* x     = (const float*)d_in[0];
    const int*   ei    = (const int*)d_in[1];
    const float* w1_l  = (const float*)d_in[2];
    const float* b1_l  = (const float*)d_in[3];
    const float* w1_r  = (const float*)d_in[4];
    const float* b1_r  = (const float*)d_in[5];
    const float* att1  = (const float*)d_in[6];
    const float* bias1 = (const float*)d_in[7];
    const float* w2_l  = (const float*)d_in[8];
    const float* b2_l  = (const float*)d_in[9];
    const float* w2_r  = (const float*)d_in[10];
    const float* b2_r  = (const float*)d_in[11];
    const float* att2  = (const float*)d_in[12];
    const float* bias2 = (const float*)d_in[13];
    const float* wcls  = (const float*)d_in[14];
    const float* bcls  = (const float*)d_in[15];
    float* out = (float*)d_out;

    char* ws = (char*)d_ws;
    f16* x_h = (f16*)ws;                                    // N*64
    f16* w1T = x_h + (size_t)N_NODES * INCHP;               // 1024*64
    f16* w2T = w1T + (size_t)D2 * INCHP;                    // 1024*512
    f16* wcT = w2T + (size_t)D2 * DCH;                      // 128*512
    f16* xlr = wcT + (size_t)OUTCHP * DCH;                  // N*1024
    f16* h   = xlr + (size_t)N_NODES * D2;                  // N*512
    int* row_ptr = (int*)(h + (size_t)N_NODES * DCH);       // N+1
    int* counts  = row_ptr + (N_NODES + 1);                 // N   } contiguous
    int* cursor  = counts + N_NODES;                        // N   } zero pair
    int* esrc    = cursor + N_NODES;                        // ET
    int* perm    = esrc + ET;                               // N
    int* bbase   = perm + N_NODES;                          // NB
    int* bcur    = bbase + NB;                              // NB

    // 1. fused prep (zeros counts/cursor/bcur; converts x; transposes weights)
    prep_all<<<5317, 256, 0, stream>>>(x, x_h, w1_l, w1_r, w2_l, w2_r, wcls,
                                       w1T, w2T, wcT, counts, bcur);
    // 2-5. CSR + degree-sorted permutation
    count_kernel<<<(ET + 255) / 256, 256, 0, stream>>>(ei, counts);
    scan_kernel<<<1, 1024, 0, stream>>>(counts, row_ptr, bbase);
    fill_kernel<<<(ET + 255) / 256, 256, 0, stream>>>(ei, row_ptr, cursor, esrc);
    perm_kernel<<<(N_NODES + 255) / 256, 256, 0, stream>>>(counts, bbase, bcur, perm);

    dim3 blk(256);
    dim3 gD(D2 / 128, (N_NODES + 127) / 128);               // 8 x 157
    dim3 gC(1, (N_NODES + 127) / 128);
    int eb = (N_NODES / 2 + 3) / 4;

    // layer 1 (fused l|r, K=64)
    gemm_f16<1, 1><<<gD, blk, 0, stream>>>(x_h, w1T, b1_l, b1_r, xlr, N_NODES, INCHP, D2, D2);
    edge_agg5<<<eb, blk, 0, stream>>>(row_ptr, esrc, perm, xlr, att1, bias1, h);
    // layer 2 (fused l|r, K=512)
    gemm_f16<1, 1><<<gD, blk, 0, stream>>>(h, w2T, b2_l, b2_r, xlr, N_NODES, DCH, D2, D2);
    edge_agg5<<<eb, blk, 0, stream>>>(row_ptr, esrc, perm, xlr, att2, bias2, h);
    // classifier (N padded 128, fp32 out)
    gemm_f16<0, 0><<<gC, blk, 0, stream>>>(h, wcT, bcls, bcls, out, N_NODES, DCH, OUTCH, OUTCH);
}

// Round 6
// 278.742 us; speedup vs baseline: 1.2094x; 1.2094x over previous
//
#include <hip/hip_runtime.h>
#include <hip/hip_bf16.h>
#include <float.h>
#include <math.h>

#define N_NODES 20000
#define N_EDGES 320000
#define ET      (N_EDGES + N_NODES)   // edges + self loops
#define ETB     ((ET + 255) / 256)     // fill blocks
#define NPB     ((N_NODES + 255) / 256)// perm blocks
#define DCH     512
#define D2      1024                   // fused l|r width
#define INCH    55
#define INCHP   64
#define OUTCH   49
#define OUTCHP  128
#define NB      130                    // degree buckets (clamped)

typedef _Float16 f16;
typedef _Float16 f16x2 __attribute__((ext_vector_type(2)));
typedef _Float16 f16x8 __attribute__((ext_vector_type(8)));
typedef float    f32x4 __attribute__((ext_vector_type(4)));

#define GPTR(p) ((const __attribute__((address_space(1))) void*)(p))
#define LPTR(p) ((__attribute__((address_space(3))) void*)(p))

// ---------------- fused prep: zeroing + conv_x + 5 weight transposes ----------
__device__ __forceinline__ void transpose_tile(const float* __restrict__ w, f16* __restrict__ o,
                                               int K, int N, int Kp, int bx, int by, int t,
                                               f16 (*tile)[66]) {
    int k0 = by * 64, n0 = bx * 64;
    #pragma unroll
    for (int r = 0; r < 16; ++r) {
        int kl = (t >> 6) + r * 4, nl = t & 63;
        int gk = k0 + kl, gn = n0 + nl;
        tile[kl][nl] = (gk < K && gn < N) ? (f16)w[(size_t)gk * N + gn] : (f16)0.f;
    }
    __syncthreads();
    #pragma unroll
    for (int r = 0; r < 16; ++r) {
        int kl = t & 63, nl = (t >> 6) + r * 4;
        o[(size_t)(n0 + nl) * Kp + k0 + kl] = tile[kl][nl];
    }
}

__global__ __launch_bounds__(256) void prep_all(const float* __restrict__ x, f16* __restrict__ x_h,
                                                const float* __restrict__ w1l, const float* __restrict__ w1r,
                                                const float* __restrict__ w2l, const float* __restrict__ w2r,
                                                const float* __restrict__ wc,
                                                f16* __restrict__ w1T, f16* __restrict__ w2T,
                                                f16* __restrict__ wcT,
                                                int* __restrict__ zeroA,   // counts+cursor contiguous (40000)
                                                int* __restrict__ bcur) {
    __shared__ f16 tile[64][66];
    int b = blockIdx.x, t = threadIdx.x;
    if (b < 157) {
        int i = b * 256 + t;
        if (i < 40000) zeroA[i] = 0;
        else if (i < 40000 + NB) bcur[i - 40000] = 0;
        return;
    }
    b -= 157;
    if (b < 5000) {
        int i = b * 256 + t;
        int r = i >> 6, c = i & 63;
        x_h[i] = (c < INCH) ? (f16)x[r * INCH + c] : (f16)0.f;
        return;
    }
    b -= 5000;
    if (b < 8)  { transpose_tile(w1l, w1T, INCH, DCH, INCHP, b, 0, t, tile); return; }
    b -= 8;
    if (b < 8)  { transpose_tile(w1r, w1T + (size_t)DCH * INCHP, INCH, DCH, INCHP, b, 0, t, tile); return; }
    b -= 8;
    if (b < 64) { transpose_tile(w2l, w2T, DCH, DCH, DCH, b & 7, b >> 3, t, tile); return; }
    b -= 64;
    if (b < 64) { transpose_tile(w2r, w2T + (size_t)DCH * DCH, DCH, DCH, DCH, b & 7, b >> 3, t, tile); return; }
    b -= 64;
    transpose_tile(wc, wcT, DCH, OUTCH, DCH, b & 1, b >> 1, t, tile);
}

// ---------------- CSR build (by dst) ----------------
__global__ void count_kernel(const int* __restrict__ ei, int* __restrict__ counts) {
    int e = blockIdx.x * blockDim.x + threadIdx.x;
    if (e >= ET) return;
    int d = (e < N_EDGES) ? ei[N_EDGES + e] : (e - N_EDGES);
    atomicAdd(&counts[d], 1);
}

// node prefix-sum + degree-bucket histogram + bucket prefix-sum
__global__ void scan_kernel(const int* __restrict__ counts, int* __restrict__ row_ptr,
                            int* __restrict__ bbase) {
    __shared__ int sdata[1024];
    __shared__ int bh[NB];
    int t = threadIdx.x;
    if (t < NB) bh[t] = 0;
    __syncthreads();
    int per = (N_NODES + 1023) / 1024;
    int b = t * per, e = min(N_NODES, b + per);
    int sum = 0;
    for (int i = b; i < e; ++i) {
        int c = counts[i];
        sum += c;
        atomicAdd(&bh[min(c, NB - 1)], 1);
    }
    sdata[t] = sum;
    __syncthreads();
    for (int off = 1; off < 1024; off <<= 1) {
        int v = (t >= off) ? sdata[t - off] : 0;
        __syncthreads();
        sdata[t] += v;
        __syncthreads();
    }
    int run = (t == 0) ? 0 : sdata[t - 1];
    if (t == 0) row_ptr[0] = 0;
    for (int i = b; i < e; ++i) { run += counts[i]; row_ptr[i + 1] = run; }
    __syncthreads();
    if (t == 0) {
        int acc = 0;
        for (int j = 0; j < NB; ++j) { int v = bh[j]; bbase[j] = acc; acc += v; }
    }
}

// fill CSR + degree-bucket scatter (hierarchical: LDS histogram -> one global
// atomic per bucket per block; chain depth <= NPB=79 instead of ~1900).
// Intra-bucket perm order is schedule-dependent, but perm only routes nodes to
// waves; each node's output is computed independently -> d_out deterministic.
__global__ __launch_bounds__(256) void fill_perm_kernel(const int* __restrict__ ei,
                                                        const int* __restrict__ row_ptr,
                                                        const int* __restrict__ counts,
                                                        const int* __restrict__ bbase,
                                                        int* __restrict__ cursor,
                                                        int* __restrict__ bcur,
                                                        int* __restrict__ esrc,
                                                        int* __restrict__ perm) {
    int blk = blockIdx.x;
    if (blk < ETB) {                        // CSR fill segment
        int e = blk * 256 + threadIdx.x;
        if (e >= ET) return;
        int s, d;
        if (e < N_EDGES) { s = ei[e]; d = ei[N_EDGES + e]; }
        else             { s = d = e - N_EDGES; }
        int pos = row_ptr[d] + atomicAdd(&cursor[d], 1);
        esrc[pos] = s;
        return;
    }
    // perm segment
    blk -= ETB;
    __shared__ int hist[NB], basep[NB];
    int t = threadIdx.x;
    for (int i = t; i < NB; i += 256) hist[i] = 0;
    __syncthreads();
    int n = blk * 256 + t;
    bool valid = n < N_NODES;
    int bkt = 0, rl = 0;
    if (valid) {
        bkt = min(counts[n], NB - 1);
        rl = atomicAdd(&hist[bkt], 1);      // LDS atomic: rank within block
    }
    __syncthreads();
    for (int i = t; i < NB; i += 256)
        if (hist[i] > 0) basep[i] = atomicAdd(&bcur[i], hist[i]);   // 1 global atomic/bucket/block
    __syncthreads();
    if (valid) perm[bbase[bkt] + basep[bkt] + rl] = n;
}

// ---------------- fp16 MFMA GEMM (m97 + T2 XOR swizzle + T1 XCD swizzle) ----------
template<int OUT_F16, int DUAL>
__global__ __launch_bounds__(256) void gemm_f16(const f16* __restrict__ A,
                                                const f16* __restrict__ BT,
                                                const float* __restrict__ bl,
                                                const float* __restrict__ br,
                                                void* __restrict__ Cout,
                                                int M, int Ka, int Nv, int ldc) {
    __shared__ __align__(16) f16 As[128][64];
    __shared__ __align__(16) f16 Bs[128][64];
    const int tid = threadIdx.x;
    const int w = tid >> 6, lane = tid & 63;
    int nbx = gridDim.x;
    int nwg = nbx * gridDim.y;
    int bid = blockIdx.y * nbx + blockIdx.x;
    if ((nwg & 7) == 0) bid = (bid & 7) * (nwg >> 3) + (bid >> 3);
    const int m0 = (bid / nbx) * 128, n0 = (bid % nbx) * 128;
    const int wr = (w >> 1) * 64, wc = (w & 1) * 64;
    const int lrow = lane & 15, lk = lane >> 4;
    const int sw = lrow & 7;

    f32x4 acc[4][4] = {};

    for (int k0 = 0; k0 < Ka; k0 += 64) {
        #pragma unroll
        for (int i = 0; i < 4; ++i) {
            int idx = tid + 256 * i;
            int row = idx >> 3;
            int cg  = (idx & 7) ^ (row & 7);
            int gm = m0 + row; gm = gm < M ? gm : M - 1;
            const f16* gp = A + (size_t)gm * Ka + k0 + cg * 8;
            f16* lp = &As[0][0] + (size_t)(w * 64 + 256 * i) * 8;
            __builtin_amdgcn_global_load_lds(GPTR(gp), LPTR(lp), 16, 0, 0);
        }
        #pragma unroll
        for (int i = 0; i < 4; ++i) {
            int idx = tid + 256 * i;
            int row = idx >> 3;
            int cg  = (idx & 7) ^ (row & 7);
            const f16* gp = BT + (size_t)(n0 + row) * Ka + k0 + cg * 8;
            f16* lp = &Bs[0][0] + (size_t)(w * 64 + 256 * i) * 8;
            __builtin_amdgcn_global_load_lds(GPTR(gp), LPTR(lp), 16, 0, 0);
        }
        __syncthreads();
        #pragma unroll
        for (int kk = 0; kk < 64; kk += 32) {
            f16x8 af[4], bf[4];
            #pragma unroll
            for (int m = 0; m < 4; ++m)
                af[m] = *(const f16x8*)&As[wr + m * 16 + lrow][(((kk >> 3) + lk) ^ sw) * 8];
            #pragma unroll
            for (int n = 0; n < 4; ++n)
                bf[n] = *(const f16x8*)&Bs[wc + n * 16 + lrow][(((kk >> 3) + lk) ^ sw) * 8];
            #pragma unroll
            for (int m = 0; m < 4; ++m)
                #pragma unroll
                for (int n = 0; n < 4; ++n)
                    acc[m][n] = __builtin_amdgcn_mfma_f32_16x16x32_f16(af[m], bf[n], acc[m][n], 0, 0, 0);
        }
        __syncthreads();
    }

    const int orow = (lane >> 4) * 4, ocol = lane & 15;
    #pragma unroll
    for (int m = 0; m < 4; ++m) {
        #pragma unroll
        for (int r = 0; r < 4; ++r) {
            int gm = m0 + wr + m * 16 + orow + r;
            if (gm >= M) continue;
            #pragma unroll
            for (int n = 0; n < 4; ++n) {
                int gn = n0 + wc + n * 16 + ocol;
                if (gn >= Nv) continue;
                float bv = DUAL ? (gn < DCH ? bl[gn] : br[gn - DCH]) : bl[gn];
                float v = acc[m][n][r] + bv;
                if (OUT_F16) ((f16*)Cout)[(size_t)gm * ldc + gn] = (f16)v;
                else         ((float*)Cout)[(size_t)gm * ldc + gn] = v;
            }
        }
    }
}

// ---------------- fused GATv2 edge phase v5 ----------------
// Two degree-matched nodes per wave (perm pairing), 1-deep gather pipeline,
// defer-max THR=8 (T13).
__global__ __launch_bounds__(256) void edge_agg5(const int* __restrict__ row_ptr,
                                                 const int* __restrict__ esrc,
                                                 const int* __restrict__ perm,
                                                 const f16* __restrict__ xlr,
                                                 const float* __restrict__ att,
                                                 const float* __restrict__ bias,
                                                 f16* __restrict__ out) {
    int wv = (blockIdx.x * 256 + threadIdx.x) >> 6;
    if (wv * 2 >= N_NODES) return;
    int n0 = perm[wv * 2], n1 = perm[wv * 2 + 1];
    int lane = threadIdx.x & 63;

    union U8 { f16x8 v; f16x2 q[4]; };
    U8 xr0, xr1;
    xr0.v = *(const f16x8*)(xlr + (size_t)n0 * D2 + DCH + lane * 8);
    xr1.v = *(const f16x8*)(xlr + (size_t)n1 * D2 + DCH + lane * 8);
    const float4* av = (const float4*)(att + lane * 8);
    float4 a0 = av[0], a1 = av[1];
    f16x2 at2[4] = { f16x2{(f16)a0.x, (f16)a0.y}, f16x2{(f16)a0.z, (f16)a0.w},
                     f16x2{(f16)a1.x, (f16)a1.y}, f16x2{(f16)a1.z, (f16)a1.w} };
    const f16x2 k02 = {(f16)0.2f, (f16)0.2f};

    int beg0 = row_ptr[n0], deg0 = row_ptr[n0 + 1] - beg0;
    int beg1 = row_ptr[n1], deg1 = row_ptr[n1 + 1] - beg1;
    int pre0 = (lane < deg0) ? esrc[beg0 + lane] : 0;
    int pre1 = (lane < deg1) ? esrc[beg1 + lane] : 0;

    float acc0[8] = {}, acc1[8] = {};
    float m0 = -FLT_MAX, m1 = -FLT_MAX, d0 = 0.f, d1 = 0.f;

    int dmax = deg0 > deg1 ? deg0 : deg1;
    int dcap = dmax < 64 ? dmax : 64;

    U8 c0, c1, x0, x1;
    {
        int s0 = __shfl(pre0, 0, 64), s1 = __shfl(pre1, 0, 64);
        c0.v = *(const f16x8*)(xlr + (size_t)s0 * D2 + lane * 8);
        c1.v = *(const f16x8*)(xlr + (size_t)s1 * D2 + lane * 8);
    }
    for (int p = 0; p < dcap; ++p) {
        int pn = (p + 1 < dcap) ? p + 1 : p;           // prefetch next (clamped)
        int t0 = __shfl(pre0, pn, 64), t1 = __shfl(pre1, pn, 64);
        x0.v = *(const f16x8*)(xlr + (size_t)t0 * D2 + lane * 8);
        x1.v = *(const f16x8*)(xlr + (size_t)t1 * D2 + lane * 8);

        float sc0 = 0.f, sc1 = 0.f;
        #pragma unroll
        for (int j = 0; j < 4; ++j) {
            f16x2 u0 = c0.q[j] + xr0.q[j];
            f16x2 u1 = c1.q[j] + xr1.q[j];
            f16x2 l0 = __builtin_elementwise_max(u0, u0 * k02);
            f16x2 l1 = __builtin_elementwise_max(u1, u1 * k02);
            sc0 = __builtin_amdgcn_fdot2(l0, at2[j], sc0, false);
            sc1 = __builtin_amdgcn_fdot2(l1, at2[j], sc1, false);
        }
        #pragma unroll
        for (int o = 8; o >= 1; o >>= 1) {
            sc0 += __shfl_xor(sc0, o, 64);
            sc1 += __shfl_xor(sc1, o, 64);
        }
        if (p >= deg0) sc0 = -INFINITY;
        if (p >= deg1) sc1 = -INFINITY;
        if (__any(sc0 > m0 + 8.f)) {                   // defer-max (T13)
            float mn = fmaxf(m0, sc0);
            float f = __expf(m0 - mn);
            d0 *= f;
            #pragma unroll
            for (int j = 0; j < 8; ++j) acc0[j] *= f;
            m0 = mn;
        }
        float w0 = __expf(sc0 - m0);
        d0 += w0;
        #pragma unroll
        for (int j = 0; j < 8; ++j) acc0[j] += w0 * (float)c0.v[j];
        if (__any(sc1 > m1 + 8.f)) {
            float mn = fmaxf(m1, sc1);
            float f = __expf(m1 - mn);
            d1 *= f;
            #pragma unroll
            for (int j = 0; j < 8; ++j) acc1[j] *= f;
            m1 = mn;
        }
        float w1 = __expf(sc1 - m1);
        d1 += w1;
        #pragma unroll
        for (int j = 0; j < 8; ++j) acc1[j] += w1 * (float)c1.v[j];
        c0 = x0; c1 = x1;
    }
    // rare tails: deg > 64
    for (int p = 64; p < deg0; ++p) {
        int s = esrc[beg0 + p];
        U8 u; u.v = *(const f16x8*)(xlr + (size_t)s * D2 + lane * 8);
        float sc0 = 0.f;
        #pragma unroll
        for (int j = 0; j < 4; ++j) {
            f16x2 t = u.q[j] + xr0.q[j];
            f16x2 l = __builtin_elementwise_max(t, t * k02);
            sc0 = __builtin_amdgcn_fdot2(l, at2[j], sc0, false);
        }
        #pragma unroll
        for (int o = 8; o >= 1; o >>= 1) sc0 += __shfl_xor(sc0, o, 64);
        if (__any(sc0 > m0 + 8.f)) {
            float mn = fmaxf(m0, sc0);
            float f = __expf(m0 - mn);
            d0 *= f;
            #pragma unroll
            for (int j = 0; j < 8; ++j) acc0[j] *= f;
            m0 = mn;
        }
        float w0 = __expf(sc0 - m0);
        d0 += w0;
        #pragma unroll
        for (int j = 0; j < 8; ++j) acc0[j] += w0 * (float)u.v[j];
    }
    for (int p = 64; p < deg1; ++p) {
        int s = esrc[beg1 + p];
        U8 u; u.v = *(const f16x8*)(xlr + (size_t)s * D2 + lane * 8);
        float sc1 = 0.f;
        #pragma unroll
        for (int j = 0; j < 4; ++j) {
            f16x2 t = u.q[j] + xr1.q[j];
            f16x2 l = __builtin_elementwise_max(t, t * k02);
            sc1 = __builtin_amdgcn_fdot2(l, at2[j], sc1, false);
        }
        #pragma unroll
        for (int o = 8; o >= 1; o >>= 1) sc1 += __shfl_xor(sc1, o, 64);
        if (__any(sc1 > m1 + 8.f)) {
            float mn = fmaxf(m1, sc1);
            float f = __expf(m1 - mn);
            d1 *= f;
            #pragma unroll
            for (int j = 0; j < 8; ++j) acc1[j] *= f;
            m1 = mn;
        }
        float w1 = __expf(sc1 - m1);
        d1 += w1;
        #pragma unroll
        for (int j = 0; j < 8; ++j) acc1[j] += w1 * (float)u.v[j];
    }

    const float4* bv = (const float4*)(bias + lane * 8);
    float4 b0 = bv[0], b1 = bv[1];
    float bf[8] = {b0.x, b0.y, b0.z, b0.w, b1.x, b1.y, b1.z, b1.w};
    float i0 = 1.f / d0, i1 = 1.f / d1;
    f16x8 o0, o1;
    #pragma unroll
    for (int j = 0; j < 8; ++j) {
        float v0 = acc0[j] * i0 + bf[j];
        float v1 = acc1[j] * i1 + bf[j];
        v0 = v0 > 0.f ? v0 : __expf(v0) - 1.f;   // ELU
        v1 = v1 > 0.f ? v1 : __expf(v1) - 1.f;
        o0[j] = (f16)v0;
        o1[j] = (f16)v1;
    }
    *(f16x8*)(out + (size_t)n0 * DCH + lane * 8) = o0;
    *(f16x8*)(out + (size_t)n1 * DCH + lane * 8) = o1;
}

// ---------------- launch ----------------
extern "C" void kernel_launch(void* const* d_in, const int* in_sizes, int n_in,
                              void* d_out, int out_size, void* d_ws, size_t ws_size,
                              hipStream_t stream) {
    const float* x     = (const float*)d_in[0];
    const int*   ei    = (const int*)d_in[1];
    const float* w1_l  = (const float*)d_in[2];
    const float* b1_l  = (const float*)d_in[3];
    const float* w1_r  = (const float*)d_in[4];
    const float* b1_r  = (const float*)d_in[5];
    const float* att1  = (const float*)d_in[6];
    const float* bias1 = (const float*)d_in[7];
    const float* w2_l  = (const float*)d_in[8];
    const float* b2_l  = (const float*)d_in[9];
    const float* w2_r  = (const float*)d_in[10];
    const float* b2_r  = (const float*)d_in[11];
    const float* att2  = (const float*)d_in[12];
    const float* bias2 = (const float*)d_in[13];
    const float* wcls  = (const float*)d_in[14];
    const float* bcls  = (const float*)d_in[15];
    float* out = (float*)d_out;

    char* ws = (char*)d_ws;
    f16* x_h = (f16*)ws;                                    // N*64
    f16* w1T = x_h + (size_t)N_NODES * INCHP;               // 1024*64
    f16* w2T = w1T + (size_t)D2 * INCHP;                    // 1024*512
    f16* wcT = w2T + (size_t)D2 * DCH;                      // 128*512
    f16* xlr = wcT + (size_t)OUTCHP * DCH;                  // N*1024
    f16* h   = xlr + (size_t)N_NODES * D2;                  // N*512
    int* row_ptr = (int*)(h + (size_t)N_NODES * DCH);       // N+1
    int* counts  = row_ptr + (N_NODES + 1);                 // N   } contiguous
    int* cursor  = counts + N_NODES;                        // N   } zero pair
    int* esrc    = cursor + N_NODES;                        // ET
    int* perm    = esrc + ET;                               // N
    int* bbase   = perm + N_NODES;                          // NB
    int* bcur    = bbase + NB;                              // NB

    // 1. fused prep (zeros counts/cursor/bcur; converts x; transposes weights)
    prep_all<<<5317, 256, 0, stream>>>(x, x_h, w1_l, w1_r, w2_l, w2_r, wcls,
                                       w1T, w2T, wcT, counts, bcur);
    // 2-4. CSR + degree-sorted permutation (fill & perm fused, hierarchical atomics)
    count_kernel<<<(ET + 255) / 256, 256, 0, stream>>>(ei, counts);
    scan_kernel<<<1, 1024, 0, stream>>>(counts, row_ptr, bbase);
    fill_perm_kernel<<<ETB + NPB, 256, 0, stream>>>(ei, row_ptr, counts, bbase,
                                                    cursor, bcur, esrc, perm);

    dim3 blk(256);
    dim3 gD(D2 / 128, (N_NODES + 127) / 128);               // 8 x 157
    dim3 gC(1, (N_NODES + 127) / 128);
    int eb = (N_NODES / 2 + 3) / 4;

    // layer 1 (fused l|r, K=64)
    gemm_f16<1, 1><<<gD, blk, 0, stream>>>(x_h, w1T, b1_l, b1_r, xlr, N_NODES, INCHP, D2, D2);
    edge_agg5<<<eb, blk, 0, stream>>>(row_ptr, esrc, perm, xlr, att1, bias1, h);
    // layer 2 (fused l|r, K=512)
    gemm_f16<1, 1><<<gD, blk, 0, stream>>>(h, w2T, b2_l, b2_r, xlr, N_NODES, DCH, D2, D2);
    edge_agg5<<<eb, blk, 0, stream>>>(row_ptr, esrc, perm, xlr, att2, bias2, h);
    // classifier (N padded 128, fp32 out)
    gemm_f16<0, 0><<<gC, blk, 0, stream>>>(h, wcT, bcls, bcls, out, N_NODES, DCH, OUTCH, OUTCH);
}

// Round 7
// 273.710 us; speedup vs baseline: 1.2316x; 1.0184x over previous
//
#include <hip/hip_runtime.h>
#include <hip/hip_bf16.h>
#include <float.h>
#include <math.h>

#define N_NODES 20000
#define N_EDGES 320000
#define ET      (N_EDGES + N_NODES)   // edges + self loops
#define ETB     ((ET + 255) / 256)     // fill blocks
#define NPB     ((N_NODES + 255) / 256)// perm blocks
#define DCH     512
#define D2      1024                   // fused l|r width
#define INCH    55
#define INCHP   64
#define OUTCH   49
#define OUTCHP  128
#define NB      130                    // degree buckets (clamped)

typedef _Float16 f16;
typedef _Float16 f16x2 __attribute__((ext_vector_type(2)));
typedef _Float16 f16x8 __attribute__((ext_vector_type(8)));
typedef float    f32x4 __attribute__((ext_vector_type(4)));

#define GPTR(p) ((const __attribute__((address_space(1))) void*)(p))
#define LPTR(p) ((__attribute__((address_space(3))) void*)(p))

// ---------------- fused prep: zeroing + conv_x + 5 weight transposes ----------
__device__ __forceinline__ void transpose_tile(const float* __restrict__ w, f16* __restrict__ o,
                                               int K, int N, int Kp, int bx, int by, int t,
                                               f16 (*tile)[66]) {
    int k0 = by * 64, n0 = bx * 64;
    #pragma unroll
    for (int r = 0; r < 16; ++r) {
        int kl = (t >> 6) + r * 4, nl = t & 63;
        int gk = k0 + kl, gn = n0 + nl;
        tile[kl][nl] = (gk < K && gn < N) ? (f16)w[(size_t)gk * N + gn] : (f16)0.f;
    }
    __syncthreads();
    #pragma unroll
    for (int r = 0; r < 16; ++r) {
        int kl = t & 63, nl = (t >> 6) + r * 4;
        o[(size_t)(n0 + nl) * Kp + k0 + kl] = tile[kl][nl];
    }
}

__global__ __launch_bounds__(256) void prep_all(const float* __restrict__ x, f16* __restrict__ x_h,
                                                const float* __restrict__ w1l, const float* __restrict__ w1r,
                                                const float* __restrict__ w2l, const float* __restrict__ w2r,
                                                const float* __restrict__ wc,
                                                f16* __restrict__ w1T, f16* __restrict__ w2T,
                                                f16* __restrict__ wcT,
                                                int* __restrict__ zeroA,   // counts+cursor contiguous (40000)
                                                int* __restrict__ bcur) {
    __shared__ f16 tile[64][66];
    int b = blockIdx.x, t = threadIdx.x;
    if (b < 157) {
        int i = b * 256 + t;
        if (i < 40000) zeroA[i] = 0;
        else if (i < 40000 + NB) bcur[i - 40000] = 0;
        return;
    }
    b -= 157;
    if (b < 5000) {
        int i = b * 256 + t;
        int r = i >> 6, c = i & 63;
        x_h[i] = (c < INCH) ? (f16)x[r * INCH + c] : (f16)0.f;
        return;
    }
    b -= 5000;
    if (b < 8)  { transpose_tile(w1l, w1T, INCH, DCH, INCHP, b, 0, t, tile); return; }
    b -= 8;
    if (b < 8)  { transpose_tile(w1r, w1T + (size_t)DCH * INCHP, INCH, DCH, INCHP, b, 0, t, tile); return; }
    b -= 8;
    if (b < 64) { transpose_tile(w2l, w2T, DCH, DCH, DCH, b & 7, b >> 3, t, tile); return; }
    b -= 64;
    if (b < 64) { transpose_tile(w2r, w2T + (size_t)DCH * DCH, DCH, DCH, DCH, b & 7, b >> 3, t, tile); return; }
    b -= 64;
    transpose_tile(wc, wcT, DCH, OUTCH, DCH, b & 1, b >> 1, t, tile);
}

// ---------------- CSR build (by dst) ----------------
__global__ void count_kernel(const int* __restrict__ ei, int* __restrict__ counts) {
    int e = blockIdx.x * blockDim.x + threadIdx.x;
    if (e >= ET) return;
    int d = (e < N_EDGES) ? ei[N_EDGES + e] : (e - N_EDGES);
    atomicAdd(&counts[d], 1);
}

// node prefix-sum + degree-bucket histogram + DESCENDING bucket prefix (LPT:
// heaviest-degree blocks dispatch first; light blocks backfill -> tight makespan)
__global__ void scan_kernel(const int* __restrict__ counts, int* __restrict__ row_ptr,
                            int* __restrict__ bbase) {
    __shared__ int sdata[1024];
    __shared__ int bh[NB];
    int t = threadIdx.x;
    if (t < NB) bh[t] = 0;
    __syncthreads();
    int per = (N_NODES + 1023) / 1024;
    int b = t * per, e = min(N_NODES, b + per);
    int sum = 0;
    for (int i = b; i < e; ++i) {
        int c = counts[i];
        sum += c;
        atomicAdd(&bh[min(c, NB - 1)], 1);
    }
    sdata[t] = sum;
    __syncthreads();
    for (int off = 1; off < 1024; off <<= 1) {
        int v = (t >= off) ? sdata[t - off] : 0;
        __syncthreads();
        sdata[t] += v;
        __syncthreads();
    }
    int run = (t == 0) ? 0 : sdata[t - 1];
    if (t == 0) row_ptr[0] = 0;
    for (int i = b; i < e; ++i) { run += counts[i]; row_ptr[i + 1] = run; }
    __syncthreads();
    if (t == 0) {
        int acc = 0;
        for (int j = NB - 1; j >= 0; --j) { bbase[j] = acc; acc += bh[j]; }  // LPT
    }
}

// fill CSR + degree-bucket scatter (hierarchical: LDS histogram -> one global
// atomic per bucket per block). Intra-bucket perm order is schedule-dependent,
// but perm only routes nodes to waves; per-node output independent -> d_out
// deterministic.
__global__ __launch_bounds__(256) void fill_perm_kernel(const int* __restrict__ ei,
                                                        const int* __restrict__ row_ptr,
                                                        const int* __restrict__ counts,
                                                        const int* __restrict__ bbase,
                                                        int* __restrict__ cursor,
                                                        int* __restrict__ bcur,
                                                        int* __restrict__ esrc,
                                                        int* __restrict__ perm) {
    int blk = blockIdx.x;
    if (blk < ETB) {                        // CSR fill segment
        int e = blk * 256 + threadIdx.x;
        if (e >= ET) return;
        int s, d;
        if (e < N_EDGES) { s = ei[e]; d = ei[N_EDGES + e]; }
        else             { s = d = e - N_EDGES; }
        int pos = row_ptr[d] + atomicAdd(&cursor[d], 1);
        esrc[pos] = s;
        return;
    }
    // perm segment
    blk -= ETB;
    __shared__ int hist[NB], basep[NB];
    int t = threadIdx.x;
    for (int i = t; i < NB; i += 256) hist[i] = 0;
    __syncthreads();
    int n = blk * 256 + t;
    bool valid = n < N_NODES;
    int bkt = 0, rl = 0;
    if (valid) {
        bkt = min(counts[n], NB - 1);
        rl = atomicAdd(&hist[bkt], 1);      // LDS atomic: rank within block
    }
    __syncthreads();
    for (int i = t; i < NB; i += 256)
        if (hist[i] > 0) basep[i] = atomicAdd(&bcur[i], hist[i]);   // 1 global atomic/bucket/block
    __syncthreads();
    if (valid) perm[bbase[bkt] + basep[bkt] + rl] = n;
}

// ---------------- fp16 MFMA GEMM (m97 + T2 XOR swizzle + T1 XCD swizzle) ----------
template<int OUT_F16, int DUAL>
__global__ __launch_bounds__(256) void gemm_f16(const f16* __restrict__ A,
                                                const f16* __restrict__ BT,
                                                const float* __restrict__ bl,
                                                const float* __restrict__ br,
                                                void* __restrict__ Cout,
                                                int M, int Ka, int Nv, int ldc) {
    __shared__ __align__(16) f16 As[128][64];
    __shared__ __align__(16) f16 Bs[128][64];
    const int tid = threadIdx.x;
    const int w = tid >> 6, lane = tid & 63;
    int nbx = gridDim.x;
    int nwg = nbx * gridDim.y;
    int bid = blockIdx.y * nbx + blockIdx.x;
    if ((nwg & 7) == 0) bid = (bid & 7) * (nwg >> 3) + (bid >> 3);
    const int m0 = (bid / nbx) * 128, n0 = (bid % nbx) * 128;
    const int wr = (w >> 1) * 64, wc = (w & 1) * 64;
    const int lrow = lane & 15, lk = lane >> 4;
    const int sw = lrow & 7;

    f32x4 acc[4][4] = {};

    for (int k0 = 0; k0 < Ka; k0 += 64) {
        #pragma unroll
        for (int i = 0; i < 4; ++i) {
            int idx = tid + 256 * i;
            int row = idx >> 3;
            int cg  = (idx & 7) ^ (row & 7);
            int gm = m0 + row; gm = gm < M ? gm : M - 1;
            const f16* gp = A + (size_t)gm * Ka + k0 + cg * 8;
            f16* lp = &As[0][0] + (size_t)(w * 64 + 256 * i) * 8;
            __builtin_amdgcn_global_load_lds(GPTR(gp), LPTR(lp), 16, 0, 0);
        }
        #pragma unroll
        for (int i = 0; i < 4; ++i) {
            int idx = tid + 256 * i;
            int row = idx >> 3;
            int cg  = (idx & 7) ^ (row & 7);
            const f16* gp = BT + (size_t)(n0 + row) * Ka + k0 + cg * 8;
            f16* lp = &Bs[0][0] + (size_t)(w * 64 + 256 * i) * 8;
            __builtin_amdgcn_global_load_lds(GPTR(gp), LPTR(lp), 16, 0, 0);
        }
        __syncthreads();
        #pragma unroll
        for (int kk = 0; kk < 64; kk += 32) {
            f16x8 af[4], bf[4];
            #pragma unroll
            for (int m = 0; m < 4; ++m)
                af[m] = *(const f16x8*)&As[wr + m * 16 + lrow][(((kk >> 3) + lk) ^ sw) * 8];
            #pragma unroll
            for (int n = 0; n < 4; ++n)
                bf[n] = *(const f16x8*)&Bs[wc + n * 16 + lrow][(((kk >> 3) + lk) ^ sw) * 8];
            #pragma unroll
            for (int m = 0; m < 4; ++m)
                #pragma unroll
                for (int n = 0; n < 4; ++n)
                    acc[m][n] = __builtin_amdgcn_mfma_f32_16x16x32_f16(af[m], bf[n], acc[m][n], 0, 0, 0);
        }
        __syncthreads();
    }

    const int orow = (lane >> 4) * 4, ocol = lane & 15;
    #pragma unroll
    for (int m = 0; m < 4; ++m) {
        #pragma unroll
        for (int r = 0; r < 4; ++r) {
            int gm = m0 + wr + m * 16 + orow + r;
            if (gm >= M) continue;
            #pragma unroll
            for (int n = 0; n < 4; ++n) {
                int gn = n0 + wc + n * 16 + ocol;
                if (gn >= Nv) continue;
                float bv = DUAL ? (gn < DCH ? bl[gn] : br[gn - DCH]) : bl[gn];
                float v = acc[m][n][r] + bv;
                if (OUT_F16) ((f16*)Cout)[(size_t)gm * ldc + gn] = (f16)v;
                else         ((float*)Cout)[(size_t)gm * ldc + gn] = v;
            }
        }
    }
}

// ---------------- fused GATv2 edge phase v6 ----------------
// Two degree-matched nodes per wave (LPT perm), ping-pong unroll-2 gather
// pipeline (loads for edge p+1 issued before computing edge p), defer-max
// THR=8 (T13). Per-edge math for both chains in PROC.
#define PROC(cc0, cc1, pp)                                                      \
  {                                                                             \
    float sc0 = 0.f, sc1 = 0.f;                                                 \
    _Pragma("unroll")                                                           \
    for (int j = 0; j < 4; ++j) {                                               \
        f16x2 u0 = cc0.q[j] + xr0.q[j];                                         \
        f16x2 u1 = cc1.q[j] + xr1.q[j];                                         \
        f16x2 l0 = __builtin_elementwise_max(u0, u0 * k02);                     \
        f16x2 l1 = __builtin_elementwise_max(u1, u1 * k02);                     \
        sc0 = __builtin_amdgcn_fdot2(l0, at2[j], sc0, false);                   \
        sc1 = __builtin_amdgcn_fdot2(l1, at2[j], sc1, false);                   \
    }                                                                           \
    _Pragma("unroll")                                                           \
    for (int o = 8; o >= 1; o >>= 1) {                                          \
        sc0 += __shfl_xor(sc0, o, 64);                                          \
        sc1 += __shfl_xor(sc1, o, 64);                                          \
    }                                                                           \
    if ((pp) >= deg0) sc0 = -INFINITY;                                          \
    if ((pp) >= deg1) sc1 = -INFINITY;                                          \
    if (__any(sc0 > m0 + 8.f)) {                                                \
        float mn = fmaxf(m0, sc0); float f = __expf(m0 - mn);                   \
        d0 *= f;                                                                \
        _Pragma("unroll") for (int j = 0; j < 8; ++j) acc0[j] *= f;             \
        m0 = mn;                                                                \
    }                                                                           \
    float w0 = __expf(sc0 - m0); d0 += w0;                                      \
    _Pragma("unroll") for (int j = 0; j < 8; ++j) acc0[j] += w0 * (float)cc0.v[j]; \
    if (__any(sc1 > m1 + 8.f)) {                                                \
        float mn = fmaxf(m1, sc1); float f = __expf(m1 - mn);                   \
        d1 *= f;                                                                \
        _Pragma("unroll") for (int j = 0; j < 8; ++j) acc1[j] *= f;             \
        m1 = mn;                                                                \
    }                                                                           \
    float w1 = __expf(sc1 - m1); d1 += w1;                                      \
    _Pragma("unroll") for (int j = 0; j < 8; ++j) acc1[j] += w1 * (float)cc1.v[j]; \
  }

__global__ __launch_bounds__(256) void edge_agg6(const int* __restrict__ row_ptr,
                                                 const int* __restrict__ esrc,
                                                 const int* __restrict__ perm,
                                                 const f16* __restrict__ xlr,
                                                 const float* __restrict__ att,
                                                 const float* __restrict__ bias,
                                                 f16* __restrict__ out) {
    int wv = (blockIdx.x * 256 + threadIdx.x) >> 6;
    if (wv * 2 >= N_NODES) return;
    int n0 = perm[wv * 2], n1 = perm[wv * 2 + 1];
    int lane = threadIdx.x & 63;

    union U8 { f16x8 v; f16x2 q[4]; };
    U8 xr0, xr1;
    xr0.v = *(const f16x8*)(xlr + (size_t)n0 * D2 + DCH + lane * 8);
    xr1.v = *(const f16x8*)(xlr + (size_t)n1 * D2 + DCH + lane * 8);
    const float4* av = (const float4*)(att + lane * 8);
    float4 a0 = av[0], a1 = av[1];
    f16x2 at2[4] = { f16x2{(f16)a0.x, (f16)a0.y}, f16x2{(f16)a0.z, (f16)a0.w},
                     f16x2{(f16)a1.x, (f16)a1.y}, f16x2{(f16)a1.z, (f16)a1.w} };
    const f16x2 k02 = {(f16)0.2f, (f16)0.2f};

    int beg0 = row_ptr[n0], deg0 = row_ptr[n0 + 1] - beg0;
    int beg1 = row_ptr[n1], deg1 = row_ptr[n1 + 1] - beg1;
    int pre0 = (lane < deg0) ? esrc[beg0 + lane] : 0;
    int pre1 = (lane < deg1) ? esrc[beg1 + lane] : 0;

    float acc0[8] = {}, acc1[8] = {};
    float m0 = -FLT_MAX, m1 = -FLT_MAX, d0 = 0.f, d1 = 0.f;

    int dmax = deg0 > deg1 ? deg0 : deg1;
    int dcap = dmax < 64 ? dmax : 64;

    U8 cA0, cA1, cB0, cB1;
    {
        int s0 = __shfl(pre0, 0, 64), s1 = __shfl(pre1, 0, 64);
        cA0.v = *(const f16x8*)(xlr + (size_t)s0 * D2 + lane * 8);
        cA1.v = *(const f16x8*)(xlr + (size_t)s1 * D2 + lane * 8);
    }
    int p = 0;
    for (; p + 1 < dcap; p += 2) {
        int t0 = __shfl(pre0, p + 1, 64), t1 = __shfl(pre1, p + 1, 64);
        cB0.v = *(const f16x8*)(xlr + (size_t)t0 * D2 + lane * 8);
        cB1.v = *(const f16x8*)(xlr + (size_t)t1 * D2 + lane * 8);
        PROC(cA0, cA1, p)
        if (p + 2 < dcap) {
            int u0 = __shfl(pre0, p + 2, 64), u1 = __shfl(pre1, p + 2, 64);
            cA0.v = *(const f16x8*)(xlr + (size_t)u0 * D2 + lane * 8);
            cA1.v = *(const f16x8*)(xlr + (size_t)u1 * D2 + lane * 8);
        }
        PROC(cB0, cB1, p + 1)
    }
    if (p < dcap) PROC(cA0, cA1, p)
    // rare tails: deg > 64 (LPT pairs similar degree, both usually long)
    for (p = 64; p < dmax; ++p) {
        int s0 = (p < deg0) ? esrc[beg0 + p] : -1;
        int s1 = (p < deg1) ? esrc[beg1 + p] : -1;
        U8 t0, t1;
        t0.v = *(const f16x8*)(xlr + (size_t)(s0 < 0 ? 0 : s0) * D2 + lane * 8);
        t1.v = *(const f16x8*)(xlr + (size_t)(s1 < 0 ? 0 : s1) * D2 + lane * 8);
        PROC(t0, t1, p)
    }

    const float4* bv = (const float4*)(bias + lane * 8);
    float4 b0 = bv[0], b1 = bv[1];
    float bf[8] = {b0.x, b0.y, b0.z, b0.w, b1.x, b1.y, b1.z, b1.w};
    float i0 = 1.f / d0, i1 = 1.f / d1;
    f16x8 o0, o1;
    #pragma unroll
    for (int j = 0; j < 8; ++j) {
        float v0 = acc0[j] * i0 + bf[j];
        float v1 = acc1[j] * i1 + bf[j];
        v0 = v0 > 0.f ? v0 : __expf(v0) - 1.f;   // ELU
        v1 = v1 > 0.f ? v1 : __expf(v1) - 1.f;
        o0[j] = (f16)v0;
        o1[j] = (f16)v1;
    }
    *(f16x8*)(out + (size_t)n0 * DCH + lane * 8) = o0;
    *(f16x8*)(out + (size_t)n1 * DCH + lane * 8) = o1;
}

// ---------------- launch ----------------
extern "C" void kernel_launch(void* const* d_in, const int* in_sizes, int n_in,
                              void* d_out, int out_size, void* d_ws, size_t ws_size,
                              hipStream_t stream) {
    const float* x     = (const float*)d_in[0];
    const int*   ei    = (const int*)d_in[1];
    const float* w1_l  = (const float*)d_in[2];
    const float* b1_l  = (const float*)d_in[3];
    const float* w1_r  = (const float*)d_in[4];
    const float* b1_r  = (const float*)d_in[5];
    const float* att1  = (const float*)d_in[6];
    const float* bias1 = (const float*)d_in[7];
    const float* w2_l  = (const float*)d_in[8];
    const float* b2_l  = (const float*)d_in[9];
    const float* w2_r  = (const float*)d_in[10];
    const float* b2_r  = (const float*)d_in[11];
    const float* att2  = (const float*)d_in[12];
    const float* bias2 = (const float*)d_in[13];
    const float* wcls  = (const float*)d_in[14];
    const float* bcls  = (const float*)d_in[15];
    float* out = (float*)d_out;

    char* ws = (char*)d_ws;
    f16* x_h = (f16*)ws;                                    // N*64
    f16* w1T = x_h + (size_t)N_NODES * INCHP;               // 1024*64
    f16* w2T = w1T + (size_t)D2 * INCHP;                    // 1024*512
    f16* wcT = w2T + (size_t)D2 * DCH;                      // 128*512
    f16* xlr = wcT + (size_t)OUTCHP * DCH;                  // N*1024
    f16* h   = xlr + (size_t)N_NODES * D2;                  // N*512
    int* row_ptr = (int*)(h + (size_t)N_NODES * DCH);       // N+1
    int* counts  = row_ptr + (N_NODES + 1);                 // N   } contiguous
    int* cursor  = counts + N_NODES;                        // N   } zero pair
    int* esrc    = cursor + N_NODES;                        // ET
    int* perm    = esrc + ET;                               // N
    int* bbase   = perm + N_NODES;                          // NB
    int* bcur    = bbase + NB;                              // NB

    // 1. fused prep (zeros counts/cursor/bcur; converts x; transposes weights)
    prep_all<<<5317, 256, 0, stream>>>(x, x_h, w1_l, w1_r, w2_l, w2_r, wcls,
                                       w1T, w2T, wcT, counts, bcur);
    // 2-4. CSR + LPT degree-sorted permutation
    count_kernel<<<(ET + 255) / 256, 256, 0, stream>>>(ei, counts);
    scan_kernel<<<1, 1024, 0, stream>>>(counts, row_ptr, bbase);
    fill_perm_kernel<<<ETB + NPB, 256, 0, stream>>>(ei, row_ptr, counts, bbase,
                                                    cursor, bcur, esrc, perm);

    dim3 blk(256);
    dim3 gD(D2 / 128, (N_NODES + 127) / 128);               // 8 x 157
    dim3 gC(1, (N_NODES + 127) / 128);
    int eb = (N_NODES / 2 + 3) / 4;

    // layer 1 (fused l|r, K=64)
    gemm_f16<1, 1><<<gD, blk, 0, stream>>>(x_h, w1T, b1_l, b1_r, xlr, N_NODES, INCHP, D2, D2);
    edge_agg6<<<eb, blk, 0, stream>>>(row_ptr, esrc, perm, xlr, att1, bias1, h);
    // layer 2 (fused l|r, K=512)
    gemm_f16<1, 1><<<gD, blk, 0, stream>>>(h, w2T, b2_l, b2_r, xlr, N_NODES, DCH, D2, D2);
    edge_agg6<<<eb, blk, 0, stream>>>(row_ptr, esrc, perm, xlr, att2, bias2, h);
    // classifier (N padded 128, fp32 out)
    gemm_f16<0, 0><<<gC, blk, 0, stream>>>(h, wcT, bcls, bcls, out, N_NODES, DCH, OUTCH, OUTCH);
}